// Round 1
// baseline (1812.277 us; speedup 1.0000x reference)
//
#include <hip/hip_runtime.h>
#include <math.h>

#define BATCH 16
#define CT    256   // total input channels = R*Cin
#define HW    64
#define OCH   64    // O
#define NK    4     // K kernels in bank
#define NR    4     // rotations

// rot90 source-index tables: w[s] = base[rotsrc[k][s]]
__device__ __constant__ int c_rotsrc[4][9] = {
    {0,1,2,3,4,5,6,7,8},
    {2,5,8,1,4,7,0,3,6},
    {8,7,6,5,4,3,2,1,0},
    {6,3,0,7,4,1,8,5,2}
};

// ---------------- kernel 1: global average pool ----------------
__global__ __launch_bounds__(256) void pool_kernel(const float* __restrict__ x,
                                                   float* __restrict__ pooled) {
    int bc = blockIdx.x;               // b*CT + ct
    int t  = threadIdx.x;
    const float* p = x + (size_t)bc * (HW*HW);
    float s = 0.f;
    for (int i = t; i < HW*HW; i += 256) s += p[i];
    for (int off = 32; off; off >>= 1) s += __shfl_down(s, off, 64);
    __shared__ float red[4];
    if ((t & 63) == 0) red[t >> 6] = s;
    __syncthreads();
    if (t == 0) pooled[bc] = (red[0] + red[1] + red[2] + red[3]) * (1.f / (HW*HW));
}

// ---------------- kernel 2: FC + sigmoid -> coeffs (B,K) ----------------
__global__ __launch_bounds__(256) void coeff_kernel(const float* __restrict__ pooled,
                                                    const float* __restrict__ fc_w,
                                                    const float* __restrict__ fc_b,
                                                    float* __restrict__ coeffs) {
    int b = blockIdx.x;
    int t = threadIdx.x;
    int w = t >> 6;     // wave -> k
    int l = t & 63;
    float s = 0.f;
    for (int c = l; c < CT; c += 64) s += pooled[b*CT + c] * fc_w[w*CT + c];
    for (int off = 32; off; off >>= 1) s += __shfl_down(s, off, 64);
    if (l == 0) {
        float z = s + fc_b[w];
        coeffs[b*NK + w] = 1.f / (1.f + expf(-z));
    }
}

// ---------------- kernel 3: mix bank -> base (B,O,Cin,3,3) ----------------
__global__ __launch_bounds__(256) void base_kernel(const float* __restrict__ coeffs,
                                                   const float* __restrict__ bank,
                                                   float* __restrict__ basew) {
    int idx = blockIdx.x * 256 + threadIdx.x;     // < BATCH*OCH*64*9
    if (idx >= BATCH*OCH*64*9) return;
    int b   = idx / (OCH*64*9);
    int rem = idx % (OCH*64*9);
    const float* cf = coeffs + b*NK;
    float v = 0.f;
    #pragma unroll
    for (int k = 0; k < NK; ++k) v += cf[k] * bank[k*(OCH*64*9) + rem];
    basew[idx] = v;
}

// ---------------- kernel 4: direct conv ----------------
// grid (8 row-tiles, 16 co-tiles, 16 b), block 256
// block: 16 output channels x (8 rows x 64 cols)
// thread: 4 co x 8 contiguous cols of one row
__global__ __launch_bounds__(256) void conv_kernel(const float* __restrict__ x,
                                                   const float* __restrict__ basew,
                                                   float* __restrict__ out) {
    const int b    = blockIdx.z;
    const int coT  = blockIdx.y;
    const int rowT = blockIdx.x;
    const int co0  = coT * 16;
    const int r0   = rowT * 8;
    const int ro   = co0 >> 6;       // rotation-out group (constant per block)
    const int o0   = co0 & 63;

    const int t      = threadIdx.x;
    const int coSlot = t >> 6;            // 0..3
    const int pxSlot = t & 63;            // 0..63
    const int prow   = pxSlot >> 3;       // 0..7 (output row within tile)
    const int pcol0  = (pxSlot & 7) * 8;  // 0,8,...,56

    __shared__ float xs[10][72];   // rows r0-1..r0+8, cols -1..64 at cc=col+1
    __shared__ float wlds[144];    // 16 co x 9

    float acc[4][8];
    #pragma unroll
    for (int i = 0; i < 4; ++i)
        #pragma unroll
        for (int j = 0; j < 8; ++j) acc[i][j] = 0.f;

    const float* xb = x     + (size_t)b * CT * (HW*HW);
    const float* bb = basew + (size_t)b * OCH * 64 * 9;

    for (int ci = 0; ci < CT; ++ci) {
        const int riq = ci >> 6;
        const int c   = ci & 63;
        const int kk  = (ro - riq) & 3;

        __syncthreads();   // protect previous iteration's reads

        // stage input tile (10 rows x 66 cols, zero halo)
        const float* xc = xb + ci * (HW*HW);
        for (int idx = t; idx < 660; idx += 256) {
            int rr = idx / 66, cc = idx % 66;
            int row = r0 - 1 + rr, col = cc - 1;
            float v = 0.f;
            if ((unsigned)row < 64u && (unsigned)col < 64u) v = xc[row*64 + col];
            xs[rr][cc] = v;
        }
        // stage rotated weights for the 16 co of this block
        if (t < 144) {
            int col_ = t / 9, s = t % 9;
            wlds[t] = bb[((o0 + col_)*64 + c)*9 + c_rotsrc[kk][s]];
        }
        __syncthreads();

        // registers: 3 rows x 10 cols of input
        float xr[3][10];
        #pragma unroll
        for (int dr = 0; dr < 3; ++dr)
            #pragma unroll
            for (int dc = 0; dc < 10; ++dc)
                xr[dr][dc] = xs[prow + dr][pcol0 + dc];

        #pragma unroll
        for (int cc2 = 0; cc2 < 4; ++cc2) {
            const float* wp = &wlds[(coSlot*4 + cc2)*9];
            float w0=wp[0],w1=wp[1],w2=wp[2],w3=wp[3],w4=wp[4],
                  w5=wp[5],w6=wp[6],w7=wp[7],w8=wp[8];
            #pragma unroll
            for (int px = 0; px < 8; ++px) {
                acc[cc2][px] += w0*xr[0][px] + w1*xr[0][px+1] + w2*xr[0][px+2]
                              + w3*xr[1][px] + w4*xr[1][px+1] + w5*xr[1][px+2]
                              + w6*xr[2][px] + w7*xr[2][px+1] + w8*xr[2][px+2];
            }
        }
    }

    #pragma unroll
    for (int cc2 = 0; cc2 < 4; ++cc2) {
        int co = co0 + coSlot*4 + cc2;
        float* op = out + (((size_t)b*CT + co)*64 + (r0 + prow))*64 + pcol0;
        #pragma unroll
        for (int px = 0; px < 8; ++px) op[px] = acc[cc2][px];
    }
}

extern "C" void kernel_launch(void* const* d_in, const int* in_sizes, int n_in,
                              void* d_out, int out_size, void* d_ws, size_t ws_size,
                              hipStream_t stream) {
    const float* x      = (const float*)d_in[0];
    const float* bank   = (const float*)d_in[1];
    const float* fc_w   = (const float*)d_in[2];
    const float* fc_b   = (const float*)d_in[3];
    float* out = (float*)d_out;

    float* pooled = (float*)d_ws;                 // 4096 floats
    float* coeffs = pooled + BATCH*CT;            // 64 floats
    float* basew  = coeffs + BATCH*NK;            // 589824 floats

    pool_kernel<<<BATCH*CT, 256, 0, stream>>>(x, pooled);
    coeff_kernel<<<BATCH, 256, 0, stream>>>(pooled, fc_w, fc_b, coeffs);
    base_kernel<<<(BATCH*OCH*64*9 + 255)/256, 256, 0, stream>>>(coeffs, bank, basew);
    conv_kernel<<<dim3(8, 16, BATCH), 256, 0, stream>>>(x, basew, out);
}

// Round 2
// 128.765 us; speedup vs baseline: 14.0742x; 14.0742x over previous
//
#include <hip/hip_runtime.h>
#include <hip/hip_bf16.h>
#include <math.h>

#define BATCH 16
#define CT    256   // total input channels = R*Cin
#define HW    64
#define OCH   64    // O
#define NK    4     // K kernels in bank
#define HP    66    // padded spatial

typedef __attribute__((ext_vector_type(4))) float f32x4;
typedef __attribute__((ext_vector_type(8))) short s16x8;

#define GLOBAL_AS __attribute__((address_space(1)))
#define LDS_AS    __attribute__((address_space(3)))

// rot90 source-index tables: w[s] = base[rotsrc[k][s]]
__device__ __constant__ int c_rotsrc[4][9] = {
    {0,1,2,3,4,5,6,7,8},
    {2,5,8,1,4,7,0,3,6},
    {8,7,6,5,4,3,2,1,0},
    {6,3,0,7,4,1,8,5,2}
};

// ---------------- kernel 1: global average pool ----------------
__global__ __launch_bounds__(256) void pool_kernel(const float* __restrict__ x,
                                                   float* __restrict__ pooled) {
    int bc = blockIdx.x;
    int t  = threadIdx.x;
    const float* p = x + (size_t)bc * (HW*HW);
    float s = 0.f;
    for (int i = t; i < HW*HW; i += 256) s += p[i];
    for (int off = 32; off; off >>= 1) s += __shfl_down(s, off, 64);
    __shared__ float red[4];
    if ((t & 63) == 0) red[t >> 6] = s;
    __syncthreads();
    if (t == 0) pooled[bc] = (red[0] + red[1] + red[2] + red[3]) * (1.f / (HW*HW));
}

// ---------------- kernel 2: FC + sigmoid -> coeffs (B,K) ----------------
__global__ __launch_bounds__(256) void coeff_kernel(const float* __restrict__ pooled,
                                                    const float* __restrict__ fc_w,
                                                    const float* __restrict__ fc_b,
                                                    float* __restrict__ coeffs) {
    int b = blockIdx.x;
    int t = threadIdx.x;
    int w = t >> 6;
    int l = t & 63;
    float s = 0.f;
    for (int c = l; c < CT; c += 64) s += pooled[b*CT + c] * fc_w[w*CT + c];
    for (int off = 32; off; off >>= 1) s += __shfl_down(s, off, 64);
    if (l == 0) {
        float z = s + fc_b[w];
        coeffs[b*NK + w] = 1.f / (1.f + expf(-z));
    }
}

// ---------------- kernel 3: mix bank -> base (B,O,Cin,3,3) ----------------
__global__ __launch_bounds__(256) void base_kernel(const float* __restrict__ coeffs,
                                                   const float* __restrict__ bank,
                                                   float* __restrict__ basew) {
    int idx = blockIdx.x * 256 + threadIdx.x;
    if (idx >= BATCH*OCH*64*9) return;
    int b   = idx / (OCH*64*9);
    int rem = idx % (OCH*64*9);
    const float* cf = coeffs + b*NK;
    float v = 0.f;
    #pragma unroll
    for (int k = 0; k < NK; ++k) v += cf[k] * bank[k*(OCH*64*9) + rem];
    basew[idx] = v;
}

// ---------------- kernel 4: build rotated bf16 weights ----------------
// W[b][s][cig=ci>>3][co][ci&7]  (bf16), co = ro*64+o, ci = ri*64+c
// value = base[b][o][c][rotsrc[(ro-ri)&3][s]]
__global__ __launch_bounds__(256) void wbuild_kernel(const float* __restrict__ basew,
                                                     __hip_bfloat16* __restrict__ Wb) {
    int idx = blockIdx.x * 256 + threadIdx.x;   // 16*256*256 = 2^20 threads
    int b  = idx >> 16;
    int co = (idx >> 8) & 255;
    int ci = idx & 255;
    int ro = co >> 6, o = co & 63;
    int ri = ci >> 6, c = ci & 63;
    int kk = (ro - ri) & 3;
    const float* bp = basew + ((size_t)(b*OCH + o)*64 + c)*9;
    #pragma unroll
    for (int s = 0; s < 9; ++s) {
        float v = bp[c_rotsrc[kk][s]];
        size_t w_idx = ((((size_t)(b*9 + s)*32 + (ci >> 3))*256 + co) << 3) + (ci & 7);
        Wb[w_idx] = __float2bfloat16(v);
    }
}

// ---------------- kernel 5: x -> padded pixel-major bf16 transpose ----------------
// xT[b][66][66][256]; border assumed pre-zeroed (memset).
__global__ __launch_bounds__(256) void xpose_kernel(const float* __restrict__ x,
                                                    __hip_bfloat16* __restrict__ xT) {
    int ci0 = blockIdx.x * 64;
    int r   = blockIdx.y;
    int b   = blockIdx.z;
    int t   = threadIdx.x;
    __shared__ __hip_bfloat16 tile[64][66];
    #pragma unroll
    for (int i = 0; i < 16; ++i) {
        int idx = i*256 + t;
        int cil = idx >> 6, c = idx & 63;
        tile[cil][c] = __float2bfloat16(x[(((size_t)(b*CT + ci0 + cil))*HW + r)*HW + c]);
    }
    __syncthreads();
    #pragma unroll
    for (int i = 0; i < 16; ++i) {
        int idx = i*256 + t;
        int cil = idx & 63, c = idx >> 6;
        xT[(((size_t)(b*HP + r + 1))*HP + (c + 1))*CT + ci0 + cil] = tile[cil][c];
    }
}

// ---------------- kernel 6: MFMA implicit-GEMM conv ----------------
// grid (8 row-tiles, 4 co-tiles, 16 b), 256 threads (4 waves).
// block tile: 64 co x (8 rows x 64 cols). wave: 4 co-frags x (2 rows x 4 col-frags).
__global__ __launch_bounds__(256, 2) void conv_mfma(
        const __hip_bfloat16* __restrict__ xT,
        const __hip_bfloat16* __restrict__ Wb,
        float* __restrict__ out) {
    const int b    = blockIdx.z;
    const int co0  = blockIdx.y * 64;
    const int r0   = blockIdx.x * 8;
    const int t    = threadIdx.x;
    const int wave = t >> 6;
    const int lane = t & 63;
    const int lo16 = lane & 15;
    const int hi4  = lane >> 4;

    // [10 rows][66 cols][32 ci] bf16 = 42240 B (+ clamp slack -> 43008 B)
    __shared__ __align__(16) short Xs[2688 * 8];

    f32x4 acc[4][8];
    #pragma unroll
    for (int f = 0; f < 4; ++f)
        #pragma unroll
        for (int p = 0; p < 8; ++p)
            acc[f][p] = (f32x4)0.f;

    const short* xTs = (const short*)xT;
    const short* Ws  = (const short*)Wb;

    for (int ch = 0; ch < 8; ++ch) {          // 32-ci chunk
        const int ci0 = ch * 32;
        __syncthreads();                       // previous chunk's reads done
        // ---- stage [10][66][32] tile via global_load_lds (16B units) ----
        for (int it = 0; it < 11; ++it) {
            int ubase = it * 256 + wave * 64;  // wave-uniform
            if (ubase < 2640) {
                int u  = ubase + lane;
                int us = u > 2639 ? 2639 : u;  // clamp source only
                int pl = us >> 2, chunk = us & 3;
                int rr = pl / 66, cc = pl - rr * 66;
                const short* src = xTs +
                    (((size_t)(b*HP + r0 + rr))*HP + cc)*CT + ci0 + chunk*8;
                __builtin_amdgcn_global_load_lds(
                    (const GLOBAL_AS void*)src,
                    (LDS_AS void*)(Xs + (size_t)ubase * 8),
                    16, 0, 0);
            }
        }
        __syncthreads();

        #pragma unroll
        for (int s = 0; s < 9; ++s) {
            const int dr = s / 3, dc = s % 3;
            // A-fragments: direct from global (L2-resident)
            const short* wp = Ws +
                ((((size_t)(b*9 + s)*32) + ch*4 + hi4)*256 + co0 + lo16)*8;
            s16x8 a0 = *(const s16x8*)(wp + 0*128);
            s16x8 a1 = *(const s16x8*)(wp + 1*128);
            s16x8 a2 = *(const s16x8*)(wp + 2*128);
            s16x8 a3 = *(const s16x8*)(wp + 3*128);
            #pragma unroll
            for (int rw = 0; rw < 2; ++rw) {
                const int prow  = wave*2 + rw;
                const int pbase = ((prow + dr)*66 + dc + lo16)*64 + hi4*16; // bytes
                #pragma unroll
                for (int cf = 0; cf < 4; ++cf) {
                    s16x8 bf = *(const s16x8*)((const char*)Xs + pbase + cf*1024);
                    acc[0][rw*4+cf] = __builtin_amdgcn_mfma_f32_16x16x32_bf16(a0, bf, acc[0][rw*4+cf], 0, 0, 0);
                    acc[1][rw*4+cf] = __builtin_amdgcn_mfma_f32_16x16x32_bf16(a1, bf, acc[1][rw*4+cf], 0, 0, 0);
                    acc[2][rw*4+cf] = __builtin_amdgcn_mfma_f32_16x16x32_bf16(a2, bf, acc[2][rw*4+cf], 0, 0, 0);
                    acc[3][rw*4+cf] = __builtin_amdgcn_mfma_f32_16x16x32_bf16(a3, bf, acc[3][rw*4+cf], 0, 0, 0);
                }
            }
        }
    }

    // ---- epilogue: D row = co (hi4*4+j), col = pixel (lo16) ----
    #pragma unroll
    for (int f = 0; f < 4; ++f)
        #pragma unroll
        for (int rw = 0; rw < 2; ++rw) {
            const int prow = r0 + wave*2 + rw;
            #pragma unroll
            for (int cf = 0; cf < 4; ++cf)
                #pragma unroll
                for (int j = 0; j < 4; ++j) {
                    int co = co0 + f*16 + hi4*4 + j;
                    out[(((size_t)(b*CT + co))*HW + prow)*HW + cf*16 + lo16] =
                        acc[f][rw*4+cf][j];
                }
        }
}

// ---------------- fallback conv (round-1, f32 VALU) ----------------
__global__ __launch_bounds__(256) void conv_kernel(const float* __restrict__ x,
                                                   const float* __restrict__ basew,
                                                   float* __restrict__ out) {
    const int b    = blockIdx.z;
    const int coT  = blockIdx.y;
    const int rowT = blockIdx.x;
    const int co0  = coT * 16;
    const int r0   = rowT * 8;
    const int ro   = co0 >> 6;
    const int o0   = co0 & 63;
    const int t      = threadIdx.x;
    const int coSlot = t >> 6;
    const int pxSlot = t & 63;
    const int prow   = pxSlot >> 3;
    const int pcol0  = (pxSlot & 7) * 8;

    __shared__ float xs[10][72];
    __shared__ float wlds[144];

    float acc[4][8];
    #pragma unroll
    for (int i = 0; i < 4; ++i)
        #pragma unroll
        for (int j = 0; j < 8; ++j) acc[i][j] = 0.f;

    const float* xb = x     + (size_t)b * CT * (HW*HW);
    const float* bb = basew + (size_t)b * OCH * 64 * 9;

    for (int ci = 0; ci < CT; ++ci) {
        const int riq = ci >> 6;
        const int c   = ci & 63;
        const int kk  = (ro - riq) & 3;
        __syncthreads();
        const float* xc = xb + ci * (HW*HW);
        for (int idx = t; idx < 660; idx += 256) {
            int rr = idx / 66, cc = idx % 66;
            int row = r0 - 1 + rr, col = cc - 1;
            float v = 0.f;
            if ((unsigned)row < 64u && (unsigned)col < 64u) v = xc[row*64 + col];
            xs[rr][cc] = v;
        }
        if (t < 144) {
            int col_ = t / 9, s = t % 9;
            wlds[t] = bb[((o0 + col_)*64 + c)*9 + c_rotsrc[kk][s]];
        }
        __syncthreads();
        float xr[3][10];
        #pragma unroll
        for (int dr = 0; dr < 3; ++dr)
            #pragma unroll
            for (int dc = 0; dc < 10; ++dc)
                xr[dr][dc] = xs[prow + dr][pcol0 + dc];
        #pragma unroll
        for (int cc2 = 0; cc2 < 4; ++cc2) {
            const float* wp2 = &wlds[(coSlot*4 + cc2)*9];
            float w0=wp2[0],w1=wp2[1],w2=wp2[2],w3=wp2[3],w4=wp2[4],
                  w5=wp2[5],w6=wp2[6],w7=wp2[7],w8=wp2[8];
            #pragma unroll
            for (int px = 0; px < 8; ++px) {
                acc[cc2][px] += w0*xr[0][px] + w1*xr[0][px+1] + w2*xr[0][px+2]
                              + w3*xr[1][px] + w4*xr[1][px+1] + w5*xr[1][px+2]
                              + w6*xr[2][px] + w7*xr[2][px+1] + w8*xr[2][px+2];
            }
        }
    }
    #pragma unroll
    for (int cc2 = 0; cc2 < 4; ++cc2) {
        int co = co0 + coSlot*4 + cc2;
        float* op = out + (((size_t)b*CT + co)*64 + (r0 + prow))*64 + pcol0;
        #pragma unroll
        for (int px = 0; px < 8; ++px) op[px] = acc[cc2][px];
    }
}

extern "C" void kernel_launch(void* const* d_in, const int* in_sizes, int n_in,
                              void* d_out, int out_size, void* d_ws, size_t ws_size,
                              hipStream_t stream) {
    const float* x      = (const float*)d_in[0];
    const float* bank   = (const float*)d_in[1];
    const float* fc_w   = (const float*)d_in[2];
    const float* fc_b   = (const float*)d_in[3];
    float* out = (float*)d_out;

    // workspace layout (bytes)
    //   pooled : 0          .. 16384        (4096 f32)
    //   coeffs : 16384      .. 16640        (64 f32)
    //   base   : 16640      .. 2375936      (589824 f32)
    //   W bf16 : 2375936    .. 21250304     (9437184 bf16)
    //   xT bf16: 21250560   .. 56934912     (17842176 bf16)
    float* pooled = (float*)d_ws;
    float* coeffs = pooled + BATCH*CT;
    float* basew  = coeffs + BATCH*NK;
    char*  wsb    = (char*)d_ws;
    __hip_bfloat16* Wb = (__hip_bfloat16*)(wsb + 2375936);
    __hip_bfloat16* xT = (__hip_bfloat16*)(wsb + 21250560);
    const size_t XT_BYTES = (size_t)BATCH*HP*HP*CT*2;   // 35684352
    const size_t NEED     = 21250560 + XT_BYTES;        // 56934912

    pool_kernel<<<BATCH*CT, 256, 0, stream>>>(x, pooled);
    coeff_kernel<<<BATCH, 256, 0, stream>>>(pooled, fc_w, fc_b, coeffs);
    base_kernel<<<(BATCH*OCH*64*9 + 255)/256, 256, 0, stream>>>(coeffs, bank, basew);

    if (ws_size >= NEED) {
        wbuild_kernel<<<(BATCH*CT*CT)/256, 256, 0, stream>>>(basew, Wb);
        hipMemsetAsync(xT, 0, XT_BYTES, stream);
        xpose_kernel<<<dim3(4, HW, BATCH), 256, 0, stream>>>(x, xT);
        conv_mfma<<<dim3(8, 4, BATCH), 256, 0, stream>>>(xT, Wb, out);
    } else {
        conv_kernel<<<dim3(8, 16, BATCH), 256, 0, stream>>>(x, basew, out);
    }
}